// Round 3
// baseline (133.658 us; speedup 1.0000x reference)
//
#include <hip/hip_runtime.h>
#include <hip/hip_bf16.h>
#include <math.h>

#define B_ 2
#define T_ 2048
#define C_ 1024
#define H_ 16
// head dim = 64

typedef __bf16 bf16x8 __attribute__((ext_vector_type(8)));
typedef __bf16 bf16x4 __attribute__((ext_vector_type(4)));
typedef float f32x4 __attribute__((ext_vector_type(4)));
typedef float f32x16 __attribute__((ext_vector_type(16)));
typedef unsigned int u32;

#if __has_builtin(__builtin_amdgcn_exp2f)
#define EXP2(x) __builtin_amdgcn_exp2f(x)
#else
#define EXP2(x) exp2f(x)
#endif

__device__ __forceinline__ void gload16(const void* g, void* l) {
    __builtin_amdgcn_global_load_lds(
        (const __attribute__((address_space(1))) void*)g,
        (__attribute__((address_space(3))) void*)l, 16, 0, 0);
}

__device__ __forceinline__ f32x4 mfma16(bf16x8 a, bf16x8 b, f32x4 c) {
    return __builtin_amdgcn_mfma_f32_16x16x32_bf16(a, b, c, 0, 0, 0);
}
__device__ __forceinline__ f32x16 mfma32(bf16x8 a, bf16x8 b, f32x16 c) {
    return __builtin_amdgcn_mfma_f32_32x32x16_bf16(a, b, c, 0, 0, 0);
}

__device__ __forceinline__ u32 cvtpk(float lo, float hi) {
    u32 r;
    asm("v_cvt_pk_bf16_f32 %0, %1, %2" : "=v"(r) : "v"(lo), "v"(hi));
    return r;
}

__device__ __forceinline__ void plane32swap(u32& a, u32& b) {
#if __has_builtin(__builtin_amdgcn_permlane32_swap)
    auto r = __builtin_amdgcn_permlane32_swap(a, b, false, false);
    a = r[0]; b = r[1];
#else
    asm("v_permlane32_swap_b32 %0, %1" : "+v"(a), "+v"(b));
#endif
}

// ---------------- fused fp32 -> bf16 casts (x, w_attn, w_proj) ----------------
// ranges are block-aligned (4096 / 3072 / 1024 blocks), so no divergence.
__global__ __launch_bounds__(256) void cast_all(const float* __restrict__ x,
                                                const float* __restrict__ wa,
                                                const float* __restrict__ wp,
                                                __bf16* __restrict__ xb,
                                                __bf16* __restrict__ wab,
                                                __bf16* __restrict__ wpb) {
    const int i = blockIdx.x * 256 + threadIdx.x;   // float4 units
    const float* src;
    __bf16* dst;
    int k;
    if (i < 1048576)            { src = x;  dst = xb;  k = i; }
    else if (i < 1048576 + 786432) { src = wa; dst = wab; k = i - 1048576; }
    else                        { src = wp; dst = wpb; k = i - (1048576 + 786432); }
    float4 v = ((const float4*)src)[k];
    bf16x4 o;
    o[0] = (__bf16)v.x; o[1] = (__bf16)v.y; o[2] = (__bf16)v.z; o[3] = (__bf16)v.w;
    ((bf16x4*)dst)[k] = o;
}

// ---------------- NT GEMM: C[m,n] = sum_k A[m,k]*B[n,k] ----------------
template <bool OUT_F32>
__global__ __launch_bounds__(256) void gemm_bt(const __bf16* __restrict__ A,
                                               const __bf16* __restrict__ Bw,
                                               void* __restrict__ Cp,
                                               int N, int K) {
    const int tid  = threadIdx.x;
    const int lane = tid & 63;
    const int w    = tid >> 6;
    const int wr = w >> 1, wc = w & 1;
    const int l15 = lane & 15, lg = lane >> 4;
    const int bm = blockIdx.y * 128, bn = blockIdx.x * 128;
    __shared__ __bf16 Asm[128 * 64];
    __shared__ __bf16 Bsm[128 * 64];
    f32x4 acc[4][4] = {};

    for (int kt = 0; kt < K; kt += 64) {
        if (kt) __syncthreads();
#pragma unroll
        for (int it = 0; it < 4; ++it) {
            const int c = it * 256 + tid;
            const int row = c >> 3, cc = (c & 7) * 8;
            gload16(A  + (size_t)(bm + row) * K + kt + cc, Asm + c * 8);
            gload16(Bw + (size_t)(bn + row) * K + kt + cc, Bsm + c * 8);
        }
        __syncthreads();
#pragma unroll
        for (int kk = 0; kk < 64; kk += 32) {
            bf16x8 af[4], bf[4];
#pragma unroll
            for (int i = 0; i < 4; ++i)
                af[i] = *(const bf16x8*)&Asm[(wr * 64 + i * 16 + l15) * 64 + kk + lg * 8];
#pragma unroll
            for (int j = 0; j < 4; ++j)
                bf[j] = *(const bf16x8*)&Bsm[(wc * 64 + j * 16 + l15) * 64 + kk + lg * 8];
#pragma unroll
            for (int i = 0; i < 4; ++i)
#pragma unroll
                for (int j = 0; j < 4; ++j)
                    acc[i][j] = mfma16(af[i], bf[j], acc[i][j]);
        }
    }
#pragma unroll
    for (int i = 0; i < 4; ++i)
#pragma unroll
        for (int j = 0; j < 4; ++j)
#pragma unroll
            for (int r = 0; r < 4; ++r) {
                const int row = bm + wr * 64 + i * 16 + lg * 4 + r;
                const int col = bn + wc * 64 + j * 16 + l15;
                if (OUT_F32)
                    ((float*)Cp)[(size_t)row * N + col] = acc[i][j][r];
                else
                    ((__bf16*)Cp)[(size_t)row * N + col] = (__bf16)acc[i][j][r];
            }
}

// ---------------- RoPE on q,k + scatter to [B,H,T,64] ----------------
// Q is additionally pre-scaled by (1/sqrt(64))*log2(e) so attn's QK^T lands
// directly in the exp2 domain (saves 32 v_mul per lane per KV tile).
__global__ __launch_bounds__(256) void rope_qk(const __bf16* __restrict__ qkv,
                                               __bf16* __restrict__ Qb,
                                               __bf16* __restrict__ Kb) {
    const int u = blockIdx.x * 256 + threadIdx.x;
    const int d = u & 31;
    const int h = (u >> 5) & 15;
    const int t = (u >> 9) & (T_ - 1);
    const int b = u >> 20;
    const size_t row = (size_t)(b * T_ + t) * (3 * C_);
    const int col = h * 64 + d;
    // inv_freq = 10000^(-d/32) = 2^(d * -log2(10000)/32)
    const float inv_freq = exp2f((float)d * -0.4152410118609203f);
    const float ang = (float)t * inv_freq;
    const float cv = __cosf(ang), sv = __sinf(ang);   // hw v_cos/v_sin
    const float q1 = (float)qkv[row + col];
    const float q2 = (float)qkv[row + col + 32];
    const float k1 = (float)qkv[row + C_ + col];
    const float k2 = (float)qkv[row + C_ + col + 32];
    const float SCLQ = 0.18033688011112042f;          // 0.125 * log2(e)
    const size_t orow = ((size_t)(b * H_ + h) * T_ + t) * 64 + d;
    Qb[orow]      = (__bf16)((q1 * cv - q2 * sv) * SCLQ);
    Qb[orow + 32] = (__bf16)((q2 * cv + q1 * sv) * SCLQ);
    Kb[orow]      = (__bf16)(k1 * cv - k2 * sv);
    Kb[orow + 32] = (__bf16)(k2 * cv + k1 * sv);
}

// ---------------- V transpose: qkv v-region -> Vt[B,H,64,T] ----------------
__global__ __launch_bounds__(256) void v_transpose(const __bf16* __restrict__ qkv,
                                                   __bf16* __restrict__ Vt) {
    const int bh = blockIdx.y, tt = blockIdx.x;
    const int b = bh >> 4, h = bh & 15;
    __shared__ __bf16 lds[64 * 65];
    const int c = threadIdx.x;
    {
        const int tr = c >> 2, dc = (c & 3) * 16;
        const __bf16* src = qkv + ((size_t)(b * T_ + tt * 64 + tr)) * (3 * C_)
                          + 2 * C_ + h * 64 + dc;
        bf16x8 v0 = *(const bf16x8*)src;
        bf16x8 v1 = *(const bf16x8*)(src + 8);
#pragma unroll
        for (int e = 0; e < 8; ++e) lds[(dc + e) * 65 + tr]     = v0[e];
#pragma unroll
        for (int e = 0; e < 8; ++e) lds[(dc + 8 + e) * 65 + tr] = v1[e];
    }
    __syncthreads();
    {
        const int d = c >> 2, tc = (c & 3) * 16;
        bf16x8 o0, o1;
#pragma unroll
        for (int e = 0; e < 8; ++e) o0[e] = lds[d * 65 + tc + e];
#pragma unroll
        for (int e = 0; e < 8; ++e) o1[e] = lds[d * 65 + tc + 8 + e];
        __bf16* dst = Vt + ((size_t)bh * 64 + d) * T_ + tt * 64 + tc;
        *(bf16x8*)dst = o0;
        *(bf16x8*)(dst + 8) = o1;
    }
}

// ---------------- causal flash attention, swapped-operand 32x32 ----------------
// Pipelined double-buffered K/V staging (T3-minimum): STAGE(j+1) issued before
// compute(j); single __syncthreads per tile (its vmcnt(0) drain lands after
// compute, so stage latency hides under ds_read/MFMA/softmax).
__global__ __launch_bounds__(256) void attn_fwd(const __bf16* __restrict__ Qb,
                                                const __bf16* __restrict__ Kb,
                                                const __bf16* __restrict__ Vt,
                                                __bf16* __restrict__ Yatt) {
    const int gid = blockIdx.x;
    const int bh = (gid & 7) * 4 + ((gid >> 3) & 3);   // same-bh blocks -> same XCD
    const int qt = 15 - (gid >> 5);                    // big (late) q-tiles first
    const int b = bh >> 4, h = bh & 15;
    const int tid = threadIdx.x, lane = tid & 63, w = tid >> 6;
    const int l31 = lane & 31, hi = lane >> 5;
    const int hi4 = hi * 4;
    __shared__ __bf16 Ksm[2][64 * 64];   // [buf][kv][d], rows XOR-swizzled
    __shared__ __bf16 Vsm[2][64 * 64];   // [buf][d][kv], rows XOR-swizzled

    const int Q0 = qt * 128 + w * 32;
    const int qg = Q0 + l31;
    const __bf16* Qp = Qb + ((size_t)bh * T_ + Q0) * 64;
    const __bf16* Kp = Kb + (size_t)bh * T_ * 64;
    const __bf16* Vp = Vt + (size_t)bh * 64 * T_;

    // Q as B-operand: col=q=l31, k = hi*8+j within d-slice [16ds,16ds+16)
    bf16x8 qf[4];
#pragma unroll
    for (int ds = 0; ds < 4; ++ds)
        qf[ds] = *(const bf16x8*)&Qp[l31 * 64 + ds * 16 + hi * 8];

    f32x16 ot[2] = {};            // O^T: d = db*32 + crow(r,hi), q = l31
    float m_run = -1e30f, l_run = 0.f;

    auto STAGE = [&](int j, int bufi) {
#pragma unroll
        for (int it = 0; it < 2; ++it) {
            const int g = it * 256 + tid;          // 16B granule id
            const int row = g >> 3;
            const int sg = (g & 7) ^ (row & 7);    // pre-swizzled source granule
            gload16(Kp + ((size_t)(j * 64 + row)) * 64 + sg * 8, &Ksm[bufi][g * 8]);
            gload16(Vp + (size_t)row * T_ + j * 64 + sg * 8,     &Vsm[bufi][g * 8]);
        }
    };

    const int jmax = 2 * (qt + 1);
    STAGE(0, 0);
    __syncthreads();                               // drain tile-0 loads

    for (int j = 0; j < jmax; ++j) {
        const int cur = j & 1;
        if (j + 1 < jmax) STAGE(j + 1, cur ^ 1);   // in flight during compute

        if (j * 64 <= Q0 + 31) {                   // wave-uniform skip of masked tiles
            // ---- S^T = K @ Q^T : lane holds q=l31, kv = a*32+crow(r,hi) ----
            f32x16 st[2] = {};
#pragma unroll
            for (int a = 0; a < 2; ++a)
#pragma unroll
                for (int ds = 0; ds < 4; ++ds) {
                    const int row = a * 32 + l31;
                    const int off = (ds * 32 + hi * 16) ^ ((row & 7) << 4);
                    bf16x8 kf = *(const bf16x8*)((const char*)Ksm[cur] + row * 128 + off);
                    st[a] = mfma32(kf, qf[ds], st[a]);
                }
            // ---- causal mask (scores already in exp2 domain via pre-scaled Q) ----
            if (j * 64 + 63 > Q0) {
#pragma unroll
                for (int a = 0; a < 2; ++a)
#pragma unroll
                    for (int r = 0; r < 16; ++r) {
                        const int kv = j * 64 + a * 32 + (r & 3) + 8 * (r >> 2) + hi4;
                        if (kv > qg) st[a][r] = -1e30f;
                    }
            }
            // ---- in-lane max tree + one cross-half shuffle ----
            float t[8];
#pragma unroll
            for (int i = 0; i < 8; ++i)
                t[i] = fmaxf(fmaxf(st[0][i], st[0][i + 8]),
                             fmaxf(st[1][i], st[1][i + 8]));
            float mx = fmaxf(fmaxf(fmaxf(t[0], t[1]), fmaxf(t[2], t[3])),
                             fmaxf(fmaxf(t[4], t[5]), fmaxf(t[6], t[7])));
            mx = fmaxf(mx, __shfl_xor(mx, 32));
            // ---- defer-max (T13) ----
            if (!__all(mx - m_run <= 10.f)) {
                const float mnew = fmaxf(m_run, mx);
                const float corr = EXP2(m_run - mnew);
                l_run *= corr;
#pragma unroll
                for (int db = 0; db < 2; ++db)
#pragma unroll
                    for (int r = 0; r < 16; ++r) ot[db][r] *= corr;
                m_run = mnew;
            }
            // ---- p = exp2(s - m); row-sum ----
            float s0 = 0.f, s1 = 0.f;
#pragma unroll
            for (int a = 0; a < 2; ++a)
#pragma unroll
                for (int r = 0; r < 16; ++r) {
                    const float e = EXP2(st[a][r] - m_run);
                    st[a][r] = e;
                    if (r & 1) s1 += e; else s0 += e;
                }
            float rs = s0 + s1;
            rs += __shfl_xor(rs, 32);
            l_run += rs;
            // ---- P^T -> B-operand frags: cvt_pk pairs + permlane32_swap ----
            bf16x8 pa[4];
#pragma unroll
            for (int ks = 0; ks < 4; ++ks) {
                const int a = ks >> 1, rb = (ks & 1) * 8;
                u32 X0 = cvtpk(st[a][rb + 0], st[a][rb + 1]);
                u32 X1 = cvtpk(st[a][rb + 2], st[a][rb + 3]);
                u32 Y0 = cvtpk(st[a][rb + 4], st[a][rb + 5]);
                u32 Y1 = cvtpk(st[a][rb + 6], st[a][rb + 7]);
                plane32swap(X0, Y0);
                plane32swap(X1, Y1);
                u32 dw[4] = {X0, X1, Y0, Y1};
                pa[ks] = *(bf16x8*)dw;
            }
            // ---- O^T += V^T-as-A @ P^T-as-B ----
#pragma unroll
            for (int ks = 0; ks < 4; ++ks)
#pragma unroll
                for (int db = 0; db < 2; ++db) {
                    const int row = db * 32 + l31;
                    const int off = (ks * 32 + hi * 16) ^ ((row & 7) << 4);
                    bf16x8 vf = *(const bf16x8*)((const char*)Vsm[cur] + row * 128 + off);
                    ot[db] = mfma32(vf, pa[ks], ot[db]);
                }
        }
        __syncthreads();   // drains next-tile loads (post-compute) + buffer handoff
    }
    // ---- epilogue: normalize, pack pairs, 8B stores ----
    const float inv = 1.f / l_run;
    __bf16* Yp = Yatt + ((size_t)(b * T_ + qg)) * C_ + h * 64;
#pragma unroll
    for (int db = 0; db < 2; ++db)
#pragma unroll
        for (int rq = 0; rq < 4; ++rq) {
            const int r = rq * 4;
            u32 dw[2];
            dw[0] = cvtpk(ot[db][r] * inv,     ot[db][r + 1] * inv);
            dw[1] = cvtpk(ot[db][r + 2] * inv, ot[db][r + 3] * inv);
            const int d = db * 32 + 8 * rq + hi4;          // (r&3)==0
            *(uint64_t*)&Yp[d] = *(uint64_t*)dw;
        }
}

extern "C" void kernel_launch(void* const* d_in, const int* in_sizes, int n_in,
                              void* d_out, int out_size, void* d_ws, size_t ws_size,
                              hipStream_t stream) {
    const float* x      = (const float*)d_in[0];
    const float* w_attn = (const float*)d_in[1];
    const float* w_proj = (const float*)d_in[2];
    float* out = (float*)d_out;
    char* ws = (char*)d_ws;

    __bf16* xb   = (__bf16*)(ws);
    __bf16* wab  = (__bf16*)(ws + 8388608);
    __bf16* wpb  = (__bf16*)(ws + 14680064);
    __bf16* qkvb = (__bf16*)(ws + 16777216);
    __bf16* Qb   = (__bf16*)(ws + 41943040);
    __bf16* Kb   = (__bf16*)(ws + 50331648);
    __bf16* Vt   = (__bf16*)(ws + 58720256);
    __bf16* Ya   = (__bf16*)(ws + 67108864);

    cast_all<<<dim3(8192), 256, 0, stream>>>(x, w_attn, w_proj, xb, wab, wpb);

    gemm_bt<false><<<dim3(3 * C_ / 128, B_ * T_ / 128), 256, 0, stream>>>(
        xb, wab, (void*)qkvb, 3 * C_, C_);

    rope_qk<<<dim3((B_ * T_ * H_ * 32) / 256), 256, 0, stream>>>(qkvb, Qb, Kb);
    v_transpose<<<dim3(T_ / 64, B_ * H_), 256, 0, stream>>>(qkvb, Vt);

    attn_fwd<<<dim3(16 * 32), 256, 0, stream>>>(Qb, Kb, Vt, Ya);

    gemm_bt<true><<<dim3(C_ / 128, B_ * T_ / 128), 256, 0, stream>>>(
        Ya, wpb, (void*)out, C_, C_);
}

// Round 4
// 111.353 us; speedup vs baseline: 1.2003x; 1.2003x over previous
//
#include <hip/hip_runtime.h>
#include <hip/hip_bf16.h>
#include <math.h>

#define B_ 2
#define T_ 2048
#define C_ 1024
#define H_ 16
// head dim = 64

typedef __bf16 bf16x8 __attribute__((ext_vector_type(8)));
typedef __bf16 bf16x4 __attribute__((ext_vector_type(4)));
typedef float f32x4 __attribute__((ext_vector_type(4)));
typedef float f32x16 __attribute__((ext_vector_type(16)));
typedef unsigned int u32;

#if __has_builtin(__builtin_amdgcn_exp2f)
#define EXP2(x) __builtin_amdgcn_exp2f(x)
#else
#define EXP2(x) exp2f(x)
#endif

__device__ __forceinline__ void gload16(const void* g, void* l) {
    __builtin_amdgcn_global_load_lds(
        (const __attribute__((address_space(1))) void*)g,
        (__attribute__((address_space(3))) void*)l, 16, 0, 0);
}

__device__ __forceinline__ f32x4 mfma16(bf16x8 a, bf16x8 b, f32x4 c) {
    return __builtin_amdgcn_mfma_f32_16x16x32_bf16(a, b, c, 0, 0, 0);
}
__device__ __forceinline__ f32x16 mfma32(bf16x8 a, bf16x8 b, f32x16 c) {
    return __builtin_amdgcn_mfma_f32_32x32x16_bf16(a, b, c, 0, 0, 0);
}

__device__ __forceinline__ u32 cvtpk(float lo, float hi) {
    u32 r;
    asm("v_cvt_pk_bf16_f32 %0, %1, %2" : "=v"(r) : "v"(lo), "v"(hi));
    return r;
}

__device__ __forceinline__ void plane32swap(u32& a, u32& b) {
#if __has_builtin(__builtin_amdgcn_permlane32_swap)
    auto r = __builtin_amdgcn_permlane32_swap(a, b, false, false);
    a = r[0]; b = r[1];
#else
    asm("v_permlane32_swap_b32 %0, %1" : "+v"(a), "+v"(b));
#endif
}

#define SCLQ 0.18033688011112042f   /* 0.125 * log2(e) */
#define NLOG2_10K_32 (-0.4152410118609203f)  /* -log2(10000)/32 */

// ---------------- fused fp32 -> bf16 casts (x, w_attn, w_proj) ----------------
__global__ __launch_bounds__(256) void cast_all(const float* __restrict__ x,
                                                const float* __restrict__ wa,
                                                const float* __restrict__ wp,
                                                __bf16* __restrict__ xb,
                                                __bf16* __restrict__ wab,
                                                __bf16* __restrict__ wpb) {
    const int i = blockIdx.x * 256 + threadIdx.x;   // float4 units
    const float* src;
    __bf16* dst;
    int k;
    if (i < 1048576)               { src = x;  dst = xb;  k = i; }
    else if (i < 1048576 + 786432) { src = wa; dst = wab; k = i - 1048576; }
    else                           { src = wp; dst = wpb; k = i - (1048576 + 786432); }
    float4 v = ((const float4*)src)[k];
    bf16x4 o;
    o[0] = (__bf16)v.x; o[1] = (__bf16)v.y; o[2] = (__bf16)v.z; o[3] = (__bf16)v.w;
    ((bf16x4*)dst)[k] = o;
}

// ---------------- qkv GEMM with fused RoPE + scatter epilogue ----------------
// C = x @ w_attn^T (M=4096, N=3072, K=1024). Instead of writing qkv, the
// epilogue applies RoPE to q/k in-register (pairs (d,d+32) live in acc frags
// (j, j+2)) and scatters Q->[B,H,T,64] (pre-scaled by SCLQ), K->[B,H,T,64],
// V->transposed [B,H,64,T].
__global__ __launch_bounds__(256) void gemm_qkv(const __bf16* __restrict__ A,
                                                const __bf16* __restrict__ Bw,
                                                __bf16* __restrict__ Qb,
                                                __bf16* __restrict__ Kb,
                                                __bf16* __restrict__ Vt) {
    const int tid  = threadIdx.x;
    const int lane = tid & 63;
    const int w    = tid >> 6;
    const int wr = w >> 1, wc = w & 1;
    const int l15 = lane & 15, lg = lane >> 4;
    const int bm = blockIdx.y * 128, bn = blockIdx.x * 128;
    const int K = C_;
    __shared__ __bf16 Asm[128 * 64];
    __shared__ __bf16 Bsm[128 * 64];
    f32x4 acc[4][4] = {};

    for (int kt = 0; kt < K; kt += 64) {
        if (kt) __syncthreads();
#pragma unroll
        for (int it = 0; it < 4; ++it) {
            const int c = it * 256 + tid;
            const int row = c >> 3, cc = (c & 7) * 8;
            gload16(A  + (size_t)(bm + row) * K + kt + cc, Asm + c * 8);
            gload16(Bw + (size_t)(bn + row) * K + kt + cc, Bsm + c * 8);
        }
        __syncthreads();
#pragma unroll
        for (int kk = 0; kk < 64; kk += 32) {
            bf16x8 af[4], bf[4];
#pragma unroll
            for (int i = 0; i < 4; ++i)
                af[i] = *(const bf16x8*)&Asm[(wr * 64 + i * 16 + l15) * 64 + kk + lg * 8];
#pragma unroll
            for (int j = 0; j < 4; ++j)
                bf[j] = *(const bf16x8*)&Bsm[(wc * 64 + j * 16 + l15) * 64 + kk + lg * 8];
#pragma unroll
            for (int i = 0; i < 4; ++i)
#pragma unroll
                for (int j = 0; j < 4; ++j)
                    acc[i][j] = mfma16(af[i], bf[j], acc[i][j]);
        }
    }
    // ---- fused epilogue ----
    const int region  = bn >> 10;                 // 0=q, 1=k, 2=v
    const int colbase = (bn & 1023) + wc * 64;    // 64-aligned
    const int h = colbase >> 6;                   // head (same for all j)
    if (region < 2) {
        __bf16* dst = region ? Kb : Qb;
        const float scl = region ? 1.0f : SCLQ;
#pragma unroll
        for (int j = 0; j < 2; ++j) {
            const int d = j * 16 + l15;           // 0..31; partner d+32 at j+2
            const float invf = exp2f((float)d * NLOG2_10K_32);
#pragma unroll
            for (int i = 0; i < 4; ++i)
#pragma unroll
                for (int r = 0; r < 4; ++r) {
                    const int row = bm + wr * 64 + i * 16 + lg * 4 + r;
                    const int b = row >> 11, t = row & (T_ - 1);
                    float sv, cv;
                    __sincosf((float)t * invf, &sv, &cv);
                    const float v1 = acc[i][j][r], v2 = acc[i][j + 2][r];
                    const float o1 = (v1 * cv - v2 * sv) * scl;
                    const float o2 = (v2 * cv + v1 * sv) * scl;
                    const size_t base = ((size_t)(b * H_ + h) * T_ + t) * 64;
                    dst[base + d]      = (__bf16)o1;
                    dst[base + d + 32] = (__bf16)o2;
                }
        }
    } else {
#pragma unroll
        for (int i = 0; i < 4; ++i)
#pragma unroll
            for (int j = 0; j < 4; ++j) {
                const int vcol = colbase + j * 16 + l15;
                const int hh = vcol >> 6, d = vcol & 63;
                const int row0 = bm + wr * 64 + i * 16 + lg * 4;
                const int b = row0 >> 11, t0 = row0 & (T_ - 1);
                u32 dw[2];
                dw[0] = cvtpk(acc[i][j][0], acc[i][j][1]);
                dw[1] = cvtpk(acc[i][j][2], acc[i][j][3]);
                *(uint64_t*)&Vt[((size_t)(b * H_ + hh) * 64 + d) * T_ + t0] =
                    *(uint64_t*)dw;
            }
    }
}

// ---------------- NT GEMM (proj): C[m,n] = sum_k A[m,k]*B[n,k], fp32 out ----
__global__ __launch_bounds__(256) void gemm_proj(const __bf16* __restrict__ A,
                                                 const __bf16* __restrict__ Bw,
                                                 float* __restrict__ Cp,
                                                 int N, int K) {
    const int tid  = threadIdx.x;
    const int lane = tid & 63;
    const int w    = tid >> 6;
    const int wr = w >> 1, wc = w & 1;
    const int l15 = lane & 15, lg = lane >> 4;
    const int bm = blockIdx.y * 128, bn = blockIdx.x * 128;
    __shared__ __bf16 Asm[128 * 64];
    __shared__ __bf16 Bsm[128 * 64];
    f32x4 acc[4][4] = {};

    for (int kt = 0; kt < K; kt += 64) {
        if (kt) __syncthreads();
#pragma unroll
        for (int it = 0; it < 4; ++it) {
            const int c = it * 256 + tid;
            const int row = c >> 3, cc = (c & 7) * 8;
            gload16(A  + (size_t)(bm + row) * K + kt + cc, Asm + c * 8);
            gload16(Bw + (size_t)(bn + row) * K + kt + cc, Bsm + c * 8);
        }
        __syncthreads();
#pragma unroll
        for (int kk = 0; kk < 64; kk += 32) {
            bf16x8 af[4], bf[4];
#pragma unroll
            for (int i = 0; i < 4; ++i)
                af[i] = *(const bf16x8*)&Asm[(wr * 64 + i * 16 + l15) * 64 + kk + lg * 8];
#pragma unroll
            for (int j = 0; j < 4; ++j)
                bf[j] = *(const bf16x8*)&Bsm[(wc * 64 + j * 16 + l15) * 64 + kk + lg * 8];
#pragma unroll
            for (int i = 0; i < 4; ++i)
#pragma unroll
                for (int j = 0; j < 4; ++j)
                    acc[i][j] = mfma16(af[i], bf[j], acc[i][j]);
        }
    }
#pragma unroll
    for (int i = 0; i < 4; ++i)
#pragma unroll
        for (int j = 0; j < 4; ++j)
#pragma unroll
            for (int r = 0; r < 4; ++r) {
                const int row = bm + wr * 64 + i * 16 + lg * 4 + r;
                const int col = bn + wc * 64 + j * 16 + l15;
                Cp[(size_t)row * N + col] = acc[i][j][r];
            }
}

// ---------------- causal flash attention, swapped-operand 32x32 ----------------
// KVBLK=128: half the barrier/drain events of the 64-tile version. R2-proven
// sync: barrier; STAGE; barrier(drain); compute. K tile [128][64] with 8-slot
// XOR swizzle; V^T tile [64][128] with 16-slot swizzle (2-way, free).
__global__ __launch_bounds__(256) void attn_fwd(const __bf16* __restrict__ Qb,
                                                const __bf16* __restrict__ Kb,
                                                const __bf16* __restrict__ Vt,
                                                __bf16* __restrict__ Yatt) {
    const int gid = blockIdx.x;
    const int bh = (gid & 7) * 4 + ((gid >> 3) & 3);   // same-bh blocks -> same XCD
    const int qt = 15 - (gid >> 5);                    // big (late) q-tiles first
    const int b = bh >> 4, h = bh & 15;
    const int tid = threadIdx.x, lane = tid & 63, w = tid >> 6;
    const int l31 = lane & 31, hi = lane >> 5;
    const int hi4 = hi * 4;
    __shared__ __bf16 Ksm[128 * 64];   // [kv][d], granule ^= (kv&7)
    __shared__ __bf16 Vsm[64 * 128];   // [d][kv], granule ^= (d&15)

    const int Q0 = qt * 128 + w * 32;
    const int qg = Q0 + l31;
    const __bf16* Qp = Qb + ((size_t)bh * T_ + Q0) * 64;
    const __bf16* Kp = Kb + (size_t)bh * T_ * 64;
    const __bf16* Vp = Vt + (size_t)bh * 64 * T_;

    // Q as B-operand: col=q=l31, k = hi*8+e within d-slice [16ds,16ds+16)
    bf16x8 qf[4];
#pragma unroll
    for (int ds = 0; ds < 4; ++ds)
        qf[ds] = *(const bf16x8*)&Qp[l31 * 64 + ds * 16 + hi * 8];

    f32x16 ot[2] = {};            // O^T: d = db*32 + crow(r,hi), q = l31
    float m_run = -1e30f, l_run = 0.f;

    const int jmax = qt + 1;      // 128-wide KV tiles
    for (int j = 0; j < jmax; ++j) {
        __syncthreads();                           // all waves done with prev tile
#pragma unroll
        for (int it = 0; it < 4; ++it) {           // stage K (16KB) + V^T (16KB)
            const int g = it * 256 + tid;          // granule id 0..1023 (16B)
            // K: row kv=g>>3 (0..127), 8 granules/row, src granule ^= (row&7)
            const int kr = g >> 3, kc = (g & 7) ^ (kr & 7);
            gload16(Kp + ((size_t)(j * 128 + kr)) * 64 + kc * 8, Ksm + g * 8);
            // V: row d=g>>4 (0..63), 16 granules/row, src granule ^= (d&15)
            const int vd = g >> 4, vg = (g & 15) ^ (vd & 15);
            gload16(Vp + (size_t)vd * T_ + j * 128 + vg * 8, Vsm + g * 8);
        }
        __syncthreads();                           // drain: tile ready

        // ---- S^T = K @ Q^T : lane holds q=l31, kv = a*32+crow(r,hi) ----
        f32x16 st[4] = {};
#pragma unroll
        for (int a = 0; a < 4; ++a)
#pragma unroll
            for (int ds = 0; ds < 4; ++ds) {
                const int row = a * 32 + l31;
                const int off = (ds * 32 + hi * 16) ^ ((row & 7) << 4);
                bf16x8 kf = *(const bf16x8*)((const char*)Ksm + row * 128 + off);
                st[a] = mfma32(kf, qf[ds], st[a]);
            }
        // ---- causal mask: only the diagonal tile needs it ----
        if (j == qt) {
#pragma unroll
            for (int a = 0; a < 4; ++a)
#pragma unroll
                for (int r = 0; r < 16; ++r) {
                    const int kv = j * 128 + a * 32 + (r & 3) + 8 * (r >> 2) + hi4;
                    if (kv > qg) st[a][r] = -1e30f;
                }
        }
        // ---- in-lane max tree + one cross-half shuffle ----
        float t8[8];
#pragma unroll
        for (int i = 0; i < 8; ++i)
            t8[i] = fmaxf(fmaxf(fmaxf(st[0][i], st[0][i + 8]),
                                fmaxf(st[1][i], st[1][i + 8])),
                          fmaxf(fmaxf(st[2][i], st[2][i + 8]),
                                fmaxf(st[3][i], st[3][i + 8])));
        float mx = fmaxf(fmaxf(fmaxf(t8[0], t8[1]), fmaxf(t8[2], t8[3])),
                         fmaxf(fmaxf(t8[4], t8[5]), fmaxf(t8[6], t8[7])));
        mx = fmaxf(mx, __shfl_xor(mx, 32));
        // ---- defer-max (T13) ----
        if (!__all(mx - m_run <= 10.f)) {
            const float mnew = fmaxf(m_run, mx);
            const float corr = EXP2(m_run - mnew);
            l_run *= corr;
#pragma unroll
            for (int db = 0; db < 2; ++db)
#pragma unroll
                for (int r = 0; r < 16; ++r) ot[db][r] *= corr;
            m_run = mnew;
        }
        // ---- p = exp2(s - m); row-sum ----
        float s0 = 0.f, s1 = 0.f;
#pragma unroll
        for (int a = 0; a < 4; ++a)
#pragma unroll
            for (int r = 0; r < 16; ++r) {
                const float e = EXP2(st[a][r] - m_run);
                st[a][r] = e;
                if (r & 1) s1 += e; else s0 += e;
            }
        float rs = s0 + s1;
        rs += __shfl_xor(rs, 32);
        l_run += rs;
        // ---- P^T -> B-operand frags: cvt_pk pairs + permlane32_swap ----
        bf16x8 pa[8];
#pragma unroll
        for (int ks = 0; ks < 8; ++ks) {
            const int a = ks >> 1, rb = (ks & 1) * 8;
            u32 X0 = cvtpk(st[a][rb + 0], st[a][rb + 1]);
            u32 X1 = cvtpk(st[a][rb + 2], st[a][rb + 3]);
            u32 Y0 = cvtpk(st[a][rb + 4], st[a][rb + 5]);
            u32 Y1 = cvtpk(st[a][rb + 6], st[a][rb + 7]);
            plane32swap(X0, Y0);
            plane32swap(X1, Y1);
            u32 dw[4] = {X0, X1, Y0, Y1};
            pa[ks] = *(bf16x8*)dw;
        }
        // ---- O^T += V^T-as-A @ P^T-as-B ----
#pragma unroll
        for (int ks = 0; ks < 8; ++ks)
#pragma unroll
            for (int db = 0; db < 2; ++db) {
                const int row = db * 32 + l31;
                const int off = ((ks * 2 + hi) ^ (row & 15)) * 16;
                bf16x8 vf = *(const bf16x8*)((const char*)Vsm + row * 256 + off);
                ot[db] = mfma32(vf, pa[ks], ot[db]);
            }
    }
    // ---- epilogue: normalize, pack pairs, 8B stores ----
    const float inv = 1.f / l_run;
    __bf16* Yp = Yatt + ((size_t)(b * T_ + qg)) * C_ + h * 64;
#pragma unroll
    for (int db = 0; db < 2; ++db)
#pragma unroll
        for (int rq = 0; rq < 4; ++rq) {
            const int r = rq * 4;
            u32 dw[2];
            dw[0] = cvtpk(ot[db][r] * inv,     ot[db][r + 1] * inv);
            dw[1] = cvtpk(ot[db][r + 2] * inv, ot[db][r + 3] * inv);
            const int d = db * 32 + 8 * rq + hi4;
            *(uint64_t*)&Yp[d] = *(uint64_t*)dw;
        }
}

extern "C" void kernel_launch(void* const* d_in, const int* in_sizes, int n_in,
                              void* d_out, int out_size, void* d_ws, size_t ws_size,
                              hipStream_t stream) {
    const float* x      = (const float*)d_in[0];
    const float* w_attn = (const float*)d_in[1];
    const float* w_proj = (const float*)d_in[2];
    float* out = (float*)d_out;
    char* ws = (char*)d_ws;

    __bf16* xb  = (__bf16*)(ws);               //  8.39 MB
    __bf16* wab = (__bf16*)(ws + 8388608);     //  6.29 MB
    __bf16* wpb = (__bf16*)(ws + 14680064);    //  2.10 MB
    __bf16* Qb  = (__bf16*)(ws + 16777216);    //  8.39 MB [B,H,T,64] roped+scaled
    __bf16* Kb  = (__bf16*)(ws + 25165824);    //  8.39 MB [B,H,T,64] roped
    __bf16* Vt  = (__bf16*)(ws + 33554432);    //  8.39 MB [B,H,64,T]
    __bf16* Ya  = (__bf16*)(ws + 41943040);    //  8.39 MB attn out [4096,1024]

    cast_all<<<dim3(8192), 256, 0, stream>>>(x, w_attn, w_proj, xb, wab, wpb);

    // qkv GEMM + fused RoPE/scatter/V-transpose (M=4096, N=3072, K=1024)
    gemm_qkv<<<dim3(3 * C_ / 128, B_ * T_ / 128), 256, 0, stream>>>(
        xb, wab, Qb, Kb, Vt);

    attn_fwd<<<dim3(16 * 32), 256, 0, stream>>>(Qb, Kb, Vt, Ya);

    // y = att_out @ w_proj^T (M=4096, N=1024, K=1024), fp32 out
    gemm_proj<<<dim3(C_ / 128, B_ * T_ / 128), 256, 0, stream>>>(
        Ya, wpb, out, C_, C_);
}

// Round 5
// 108.859 us; speedup vs baseline: 1.2278x; 1.0229x over previous
//
#include <hip/hip_runtime.h>
#include <hip/hip_bf16.h>
#include <math.h>

#define B_ 2
#define T_ 2048
#define C_ 1024
#define H_ 16
// head dim = 64

typedef __bf16 bf16x8 __attribute__((ext_vector_type(8)));
typedef __bf16 bf16x4 __attribute__((ext_vector_type(4)));
typedef float f32x4 __attribute__((ext_vector_type(4)));
typedef float f32x16 __attribute__((ext_vector_type(16)));
typedef unsigned int u32;

#if __has_builtin(__builtin_amdgcn_exp2f)
#define EXP2(x) __builtin_amdgcn_exp2f(x)
#else
#define EXP2(x) exp2f(x)
#endif

__device__ __forceinline__ void gload16(const void* g, void* l) {
    __builtin_amdgcn_global_load_lds(
        (const __attribute__((address_space(1))) void*)g,
        (__attribute__((address_space(3))) void*)l, 16, 0, 0);
}

__device__ __forceinline__ f32x4 mfma16(bf16x8 a, bf16x8 b, f32x4 c) {
    return __builtin_amdgcn_mfma_f32_16x16x32_bf16(a, b, c, 0, 0, 0);
}
__device__ __forceinline__ f32x16 mfma32(bf16x8 a, bf16x8 b, f32x16 c) {
    return __builtin_amdgcn_mfma_f32_32x32x16_bf16(a, b, c, 0, 0, 0);
}

__device__ __forceinline__ u32 cvtpk(float lo, float hi) {
    u32 r;
    asm("v_cvt_pk_bf16_f32 %0, %1, %2" : "=v"(r) : "v"(lo), "v"(hi));
    return r;
}

__device__ __forceinline__ void plane32swap(u32& a, u32& b) {
#if __has_builtin(__builtin_amdgcn_permlane32_swap)
    auto r = __builtin_amdgcn_permlane32_swap(a, b, false, false);
    a = r[0]; b = r[1];
#else
    asm("v_permlane32_swap_b32 %0, %1" : "+v"(a), "+v"(b));
#endif
}

#define SCLQ 0.18033688011112042f   /* 0.125 * log2(e) */
#define NLOG2_10K_32 (-0.4152410118609203f)  /* -log2(10000)/32 */

// ---------------- fused fp32 -> bf16 casts (x, w_attn, w_proj) ----------------
__global__ __launch_bounds__(256) void cast_all(const float* __restrict__ x,
                                                const float* __restrict__ wa,
                                                const float* __restrict__ wp,
                                                __bf16* __restrict__ xb,
                                                __bf16* __restrict__ wab,
                                                __bf16* __restrict__ wpb) {
    const int i = blockIdx.x * 256 + threadIdx.x;   // float4 units
    const float* src;
    __bf16* dst;
    int k;
    if (i < 1048576)               { src = x;  dst = xb;  k = i; }
    else if (i < 1048576 + 786432) { src = wa; dst = wab; k = i - 1048576; }
    else                           { src = wp; dst = wpb; k = i - (1048576 + 786432); }
    float4 v = ((const float4*)src)[k];
    bf16x4 o;
    o[0] = (__bf16)v.x; o[1] = (__bf16)v.y; o[2] = (__bf16)v.z; o[3] = (__bf16)v.w;
    ((bf16x4*)dst)[k] = o;
}

// ---------------- qkv GEMM with fused RoPE + scatter epilogue ----------------
__global__ __launch_bounds__(256) void gemm_qkv(const __bf16* __restrict__ A,
                                                const __bf16* __restrict__ Bw,
                                                __bf16* __restrict__ Qb,
                                                __bf16* __restrict__ Kb,
                                                __bf16* __restrict__ Vt) {
    const int tid  = threadIdx.x;
    const int lane = tid & 63;
    const int w    = tid >> 6;
    const int wr = w >> 1, wc = w & 1;
    const int l15 = lane & 15, lg = lane >> 4;
    const int bm = blockIdx.y * 128, bn = blockIdx.x * 128;
    const int K = C_;
    __shared__ __bf16 Asm[128 * 64];
    __shared__ __bf16 Bsm[128 * 64];
    f32x4 acc[4][4] = {};

    for (int kt = 0; kt < K; kt += 64) {
        if (kt) __syncthreads();
#pragma unroll
        for (int it = 0; it < 4; ++it) {
            const int c = it * 256 + tid;
            const int row = c >> 3, cc = (c & 7) * 8;
            gload16(A  + (size_t)(bm + row) * K + kt + cc, Asm + c * 8);
            gload16(Bw + (size_t)(bn + row) * K + kt + cc, Bsm + c * 8);
        }
        __syncthreads();
#pragma unroll
        for (int kk = 0; kk < 64; kk += 32) {
            bf16x8 af[4], bf[4];
#pragma unroll
            for (int i = 0; i < 4; ++i)
                af[i] = *(const bf16x8*)&Asm[(wr * 64 + i * 16 + l15) * 64 + kk + lg * 8];
#pragma unroll
            for (int j = 0; j < 4; ++j)
                bf[j] = *(const bf16x8*)&Bsm[(wc * 64 + j * 16 + l15) * 64 + kk + lg * 8];
#pragma unroll
            for (int i = 0; i < 4; ++i)
#pragma unroll
                for (int j = 0; j < 4; ++j)
                    acc[i][j] = mfma16(af[i], bf[j], acc[i][j]);
        }
    }
    // ---- fused epilogue: RoPE q/k in-register, scatter Q/K/V^T ----
    const int region  = bn >> 10;                 // 0=q, 1=k, 2=v
    const int colbase = (bn & 1023) + wc * 64;    // 64-aligned
    const int h = colbase >> 6;
    if (region < 2) {
        __bf16* dst = region ? Kb : Qb;
        const float scl = region ? 1.0f : SCLQ;
#pragma unroll
        for (int j = 0; j < 2; ++j) {
            const int d = j * 16 + l15;           // 0..31; partner d+32 at j+2
            const float invf = exp2f((float)d * NLOG2_10K_32);
#pragma unroll
            for (int i = 0; i < 4; ++i)
#pragma unroll
                for (int r = 0; r < 4; ++r) {
                    const int row = bm + wr * 64 + i * 16 + lg * 4 + r;
                    const int b = row >> 11, t = row & (T_ - 1);
                    float sv, cv;
                    __sincosf((float)t * invf, &sv, &cv);
                    const float v1 = acc[i][j][r], v2 = acc[i][j + 2][r];
                    const float o1 = (v1 * cv - v2 * sv) * scl;
                    const float o2 = (v2 * cv + v1 * sv) * scl;
                    const size_t base = ((size_t)(b * H_ + h) * T_ + t) * 64;
                    dst[base + d]      = (__bf16)o1;
                    dst[base + d + 32] = (__bf16)o2;
                }
        }
    } else {
#pragma unroll
        for (int i = 0; i < 4; ++i)
#pragma unroll
            for (int j = 0; j < 4; ++j) {
                const int vcol = colbase + j * 16 + l15;
                const int hh = vcol >> 6, d = vcol & 63;
                const int row0 = bm + wr * 64 + i * 16 + lg * 4;
                const int b = row0 >> 11, t0 = row0 & (T_ - 1);
                u32 dw[2];
                dw[0] = cvtpk(acc[i][j][0], acc[i][j][1]);
                dw[1] = cvtpk(acc[i][j][2], acc[i][j][3]);
                *(uint64_t*)&Vt[((size_t)(b * H_ + hh) * 64 + d) * T_ + t0] =
                    *(uint64_t*)dw;
            }
    }
}

// ---------------- proj GEMM: BM=64 for 512 blocks (2 blocks/CU) ----------------
__global__ __launch_bounds__(256) void gemm_proj(const __bf16* __restrict__ A,
                                                 const __bf16* __restrict__ Bw,
                                                 float* __restrict__ Cp,
                                                 int N, int K) {
    const int tid  = threadIdx.x;
    const int lane = tid & 63;
    const int w    = tid >> 6;
    const int wr = w >> 1, wc = w & 1;
    const int l15 = lane & 15, lg = lane >> 4;
    const int bm = blockIdx.y * 64, bn = blockIdx.x * 128;
    __shared__ __bf16 Asm[64 * 64];
    __shared__ __bf16 Bsm[128 * 64];
    f32x4 acc[2][4] = {};

    for (int kt = 0; kt < K; kt += 64) {
        if (kt) __syncthreads();
#pragma unroll
        for (int it = 0; it < 2; ++it) {          // A: 512 granules
            const int g = it * 256 + tid;
            const int row = g >> 3, cc = (g & 7) * 8;
            gload16(A + (size_t)(bm + row) * K + kt + cc, Asm + g * 8);
        }
#pragma unroll
        for (int it = 0; it < 4; ++it) {          // B: 1024 granules
            const int g = it * 256 + tid;
            const int row = g >> 3, cc = (g & 7) * 8;
            gload16(Bw + (size_t)(bn + row) * K + kt + cc, Bsm + g * 8);
        }
        __syncthreads();
#pragma unroll
        for (int kk = 0; kk < 64; kk += 32) {
            bf16x8 af[2], bf[4];
#pragma unroll
            for (int i = 0; i < 2; ++i)
                af[i] = *(const bf16x8*)&Asm[(wr * 32 + i * 16 + l15) * 64 + kk + lg * 8];
#pragma unroll
            for (int j = 0; j < 4; ++j)
                bf[j] = *(const bf16x8*)&Bsm[(wc * 64 + j * 16 + l15) * 64 + kk + lg * 8];
#pragma unroll
            for (int i = 0; i < 2; ++i)
#pragma unroll
                for (int j = 0; j < 4; ++j)
                    acc[i][j] = mfma16(af[i], bf[j], acc[i][j]);
        }
    }
#pragma unroll
    for (int i = 0; i < 2; ++i)
#pragma unroll
        for (int j = 0; j < 4; ++j)
#pragma unroll
            for (int r = 0; r < 4; ++r) {
                const int row = bm + wr * 32 + i * 16 + lg * 4 + r;
                const int col = bn + wc * 64 + j * 16 + l15;
                Cp[(size_t)row * N + col] = acc[i][j][r];
            }
}

// ---------------- causal flash attention, swapped-operand 32x32 ----------------
// KVBLK=128, double-buffered with COUNTED vmcnt (raw s_barrier, not
// __syncthreads -- __syncthreads drains vmcnt(0) and kills the prefetch,
// which is why the R3 variant regressed). Per tile:
//   s_barrier (compute j-1 done) ; STAGE(j+1) ; vmcnt(8) [tile j ready,
//   tile j+1's 8 loads stay in flight across compute] ; s_barrier ; compute.
__global__ __launch_bounds__(256) void attn_fwd(const __bf16* __restrict__ Qb,
                                                const __bf16* __restrict__ Kb,
                                                const __bf16* __restrict__ Vt,
                                                __bf16* __restrict__ Yatt) {
    const int gid = blockIdx.x;
    const int bh = (gid & 7) * 4 + ((gid >> 3) & 3);   // same-bh blocks -> same XCD
    const int qq = gid >> 5;                           // 0..15
    const int qt = (qq < 8) ? (15 - qq) : (qq - 8);    // CU pair sums to 17 tiles
    const int b = bh >> 4, h = bh & 15;
    const int tid = threadIdx.x, lane = tid & 63, w = tid >> 6;
    const int l31 = lane & 31, hi = lane >> 5;
    const int hi4 = hi * 4;
    __shared__ __bf16 Ksm[2][128 * 64];   // [buf][kv][d], granule ^= (kv&7)
    __shared__ __bf16 Vsm[2][64 * 128];   // [buf][d][kv], granule ^= (d&15)

    const int Q0 = qt * 128 + w * 32;
    const int qg = Q0 + l31;
    const __bf16* Qp = Qb + ((size_t)bh * T_ + Q0) * 64;
    const __bf16* Kp = Kb + (size_t)bh * T_ * 64;
    const __bf16* Vp = Vt + (size_t)bh * 64 * T_;

    auto STAGE = [&](int j) {
        __bf16* Ks = Ksm[j & 1];
        __bf16* Vs = Vsm[j & 1];
#pragma unroll
        for (int it = 0; it < 4; ++it) {           // 8 loads per thread total
            const int g = it * 256 + tid;          // granule id 0..1023 (16B)
            const int kr = g >> 3, kc = (g & 7) ^ (kr & 7);
            gload16(Kp + ((size_t)(j * 128 + kr)) * 64 + kc * 8, Ks + g * 8);
            const int vd = g >> 4, vg = (g & 15) ^ (vd & 15);
            gload16(Vp + (size_t)vd * T_ + j * 128 + vg * 8, Vs + g * 8);
        }
    };

    const int jmax = qt + 1;
    STAGE(0);

    // Q as B-operand: col=q=l31, k = hi*8+e within d-slice [16ds,16ds+16)
    bf16x8 qf[4];
#pragma unroll
    for (int ds = 0; ds < 4; ++ds)
        qf[ds] = *(const bf16x8*)&Qp[l31 * 64 + ds * 16 + hi * 8];

    f32x16 ot[2] = {};            // O^T: d = db*32 + crow(r,hi), q = l31
    float m_run = -1e30f, l_run = 0.f;

    for (int j = 0; j < jmax; ++j) {
        const int cur = j & 1;
        __builtin_amdgcn_s_barrier();              // all waves done with prev tile
        if (j + 1 < jmax) {
            STAGE(j + 1);
            asm volatile("s_waitcnt vmcnt(8)" ::: "memory");   // tile j ready
        } else {
            asm volatile("s_waitcnt vmcnt(0)" ::: "memory");
        }
        __builtin_amdgcn_s_barrier();              // collective: tile j ready
        __builtin_amdgcn_sched_barrier(0);

        // ---- S^T = K @ Q^T : lane holds q=l31, kv = a*32+crow(r,hi) ----
        f32x16 st[4] = {};
#pragma unroll
        for (int a = 0; a < 4; ++a)
#pragma unroll
            for (int ds = 0; ds < 4; ++ds) {
                const int row = a * 32 + l31;
                const int off = (ds * 32 + hi * 16) ^ ((row & 7) << 4);
                bf16x8 kf = *(const bf16x8*)((const char*)Ksm[cur] + row * 128 + off);
                st[a] = mfma32(kf, qf[ds], st[a]);
            }
        // ---- causal mask: only the diagonal tile needs it ----
        if (j == qt) {
#pragma unroll
            for (int a = 0; a < 4; ++a)
#pragma unroll
                for (int r = 0; r < 16; ++r) {
                    const int kv = j * 128 + a * 32 + (r & 3) + 8 * (r >> 2) + hi4;
                    if (kv > qg) st[a][r] = -1e30f;
                }
        }
        // ---- in-lane max tree + one cross-half shuffle ----
        float t8[8];
#pragma unroll
        for (int i = 0; i < 8; ++i)
            t8[i] = fmaxf(fmaxf(fmaxf(st[0][i], st[0][i + 8]),
                                fmaxf(st[1][i], st[1][i + 8])),
                          fmaxf(fmaxf(st[2][i], st[2][i + 8]),
                                fmaxf(st[3][i], st[3][i + 8])));
        float mx = fmaxf(fmaxf(fmaxf(t8[0], t8[1]), fmaxf(t8[2], t8[3])),
                         fmaxf(fmaxf(t8[4], t8[5]), fmaxf(t8[6], t8[7])));
        mx = fmaxf(mx, __shfl_xor(mx, 32));
        // ---- defer-max (T13) ----
        if (!__all(mx - m_run <= 10.f)) {
            const float mnew = fmaxf(m_run, mx);
            const float corr = EXP2(m_run - mnew);
            l_run *= corr;
#pragma unroll
            for (int db = 0; db < 2; ++db)
#pragma unroll
                for (int r = 0; r < 16; ++r) ot[db][r] *= corr;
            m_run = mnew;
        }
        // ---- p = exp2(s - m); row-sum ----
        float s0 = 0.f, s1 = 0.f;
#pragma unroll
        for (int a = 0; a < 4; ++a)
#pragma unroll
            for (int r = 0; r < 16; ++r) {
                const float e = EXP2(st[a][r] - m_run);
                st[a][r] = e;
                if (r & 1) s1 += e; else s0 += e;
            }
        float rs = s0 + s1;
        rs += __shfl_xor(rs, 32);
        l_run += rs;
        // ---- P^T -> B-operand frags: cvt_pk pairs + permlane32_swap ----
        bf16x8 pa[8];
#pragma unroll
        for (int ks = 0; ks < 8; ++ks) {
            const int a = ks >> 1, rb = (ks & 1) * 8;
            u32 X0 = cvtpk(st[a][rb + 0], st[a][rb + 1]);
            u32 X1 = cvtpk(st[a][rb + 2], st[a][rb + 3]);
            u32 Y0 = cvtpk(st[a][rb + 4], st[a][rb + 5]);
            u32 Y1 = cvtpk(st[a][rb + 6], st[a][rb + 7]);
            plane32swap(X0, Y0);
            plane32swap(X1, Y1);
            u32 dw[4] = {X0, X1, Y0, Y1};
            pa[ks] = *(bf16x8*)dw;
        }
        // ---- O^T += V^T-as-A @ P^T-as-B ----
#pragma unroll
        for (int ks = 0; ks < 8; ++ks)
#pragma unroll
            for (int db = 0; db < 2; ++db) {
                const int row = db * 32 + l31;
                const int off = ((ks * 2 + hi) ^ (row & 15)) * 16;
                bf16x8 vf = *(const bf16x8*)((const char*)Vsm[cur] + row * 256 + off);
                ot[db] = mfma32(vf, pa[ks], ot[db]);
            }
    }
    // ---- epilogue: normalize, pack pairs, 8B stores ----
    const float inv = 1.f / l_run;
    __bf16* Yp = Yatt + ((size_t)(b * T_ + qg)) * C_ + h * 64;
#pragma unroll
    for (int db = 0; db < 2; ++db)
#pragma unroll
        for (int rq = 0; rq < 4; ++rq) {
            const int r = rq * 4;
            u32 dw[2];
            dw[0] = cvtpk(ot[db][r] * inv,     ot[db][r + 1] * inv);
            dw[1] = cvtpk(ot[db][r + 2] * inv, ot[db][r + 3] * inv);
            const int d = db * 32 + 8 * rq + hi4;
            *(uint64_t*)&Yp[d] = *(uint64_t*)dw;
        }
}

extern "C" void kernel_launch(void* const* d_in, const int* in_sizes, int n_in,
                              void* d_out, int out_size, void* d_ws, size_t ws_size,
                              hipStream_t stream) {
    const float* x      = (const float*)d_in[0];
    const float* w_attn = (const float*)d_in[1];
    const float* w_proj = (const float*)d_in[2];
    float* out = (float*)d_out;
    char* ws = (char*)d_ws;

    __bf16* xb  = (__bf16*)(ws);               //  8.39 MB
    __bf16* wab = (__bf16*)(ws + 8388608);     //  6.29 MB
    __bf16* wpb = (__bf16*)(ws + 14680064);    //  2.10 MB
    __bf16* Qb  = (__bf16*)(ws + 16777216);    //  8.39 MB [B,H,T,64] roped+scaled
    __bf16* Kb  = (__bf16*)(ws + 25165824);    //  8.39 MB [B,H,T,64] roped
    __bf16* Vt  = (__bf16*)(ws + 33554432);    //  8.39 MB [B,H,64,T]
    __bf16* Ya  = (__bf16*)(ws + 41943040);    //  8.39 MB attn out [4096,1024]

    cast_all<<<dim3(8192), 256, 0, stream>>>(x, w_attn, w_proj, xb, wab, wpb);

    gemm_qkv<<<dim3(3 * C_ / 128, B_ * T_ / 128), 256, 0, stream>>>(
        xb, wab, Qb, Kb, Vt);

    attn_fwd<<<dim3(16 * 32), 256, 0, stream>>>(Qb, Kb, Vt, Ya);

    gemm_proj<<<dim3(C_ / 128, B_ * T_ / 64), 256, 0, stream>>>(
        Ya, wpb, out, C_, C_);
}